// Round 10
// baseline (217.388 us; speedup 1.0000x reference)
//
#include <hip/hip_runtime.h>
#include <hip/hip_fp16.h>
#include <math.h>

// DigitCaps dynamic routing, MI355X (gfx950). Round 10: MLP-maximized routes.
// B=256, I=1152 (dim 8), O=10 (dim 16), 3 routing iters.
//
// R9 post-mortem: routes stuck at ~45 us (2.1 TB/s on 94 MB) across three
// implementations; VALU floor ~9 us, per-CU byte rate trivial -> latency-bound
// with MLP<=2. Fix: load the ENTIRE per-thread ws slice (9 groups x 10 o,
// packed 45 dwords) into registers upfront (18 wide loads, fully unrolled),
// then compute from registers. 512-thr blocks, grid 1024 (b x quarter),
// launch_bounds(512,4) = 128 VGPR budget (live ~95; R6/R7 taught us to keep
// fat margin or the compiler spills to scratch).
//
// ws layout: [b][g 0..71][pos 0..255], g = i>>4, pos = (i&15)*16+d.
// k_uhat stores and route loads are both 1 KB/wave coalesced.
//
// b_ij identity: logits at iter k = u.(v0+..+v_{k-1}) = u.vsum.
// Pipeline: k_uhat -> k_route<1> (inline vsum0) -> k_route<2> -> k_final.

constexpr int Bc  = 256;
constexpr int Ic  = 1152;
constexpr int Oc  = 10;
constexpr int DOc = 16;
constexpr int ODc = 160;
constexpr int ITILES = 72;

// Sum over the aligned 16-lane group, result in all 16 lanes. Pure VALU (DPP).
__device__ __forceinline__ float dpp16_sum(float v) {
    int s;
    s = __builtin_amdgcn_update_dpp(0, __float_as_int(v), 0xB1, 0xF, 0xF, true);
    v += __int_as_float(s);
    s = __builtin_amdgcn_update_dpp(0, __float_as_int(v), 0x4E, 0xF, 0xF, true);
    v += __int_as_float(s);
    s = __builtin_amdgcn_update_dpp(0, __float_as_int(v), 0x124, 0xF, 0xF, true);
    v += __int_as_float(s);
    s = __builtin_amdgcn_update_dpp(0, __float_as_int(v), 0x128, 0xF, 0xF, true);
    v += __int_as_float(s);
    return v;
}

__device__ __forceinline__ unsigned int pack_h2(float a, float b) {
    __half2 h = __floats2half2_rn(a, b);
    unsigned int u;
    __builtin_memcpy(&u, &h, 4);
    return u;
}

__device__ __forceinline__ float2 unpack_h2(unsigned int u) {
    __half2 h;
    __builtin_memcpy(&h, &u, 4);
    return __half22float2(h);
}

// ---------------------------------------------------------------- K1
// R9's proven kernel (46 us, VGPR 64); only the ws indexing changed.
// grid 72 itiles x 16 btiles, 256 threads.
__global__ __launch_bounds__(256, 4) void k_uhat(const float* __restrict__ x,
                                                 const float* __restrict__ W,
                                                 uint4* __restrict__ ws4,
                                                 unsigned int* __restrict__ ws1,
                                                 float* __restrict__ partial) {
    const int bx    = blockIdx.x;
    const int itile = bx % ITILES;
    const int btile = bx / ITILES;
    const int t     = threadIdx.x;
    const int d     = t & 15;
    const int il    = t >> 4;
    const int w     = t >> 6;
    const int i     = itile * 16 + il;
    const int b0    = btile * 16;

    __shared__ __align__(16) float xs[16 * 128];       //  8 KB [bb][il*8+k]
    __shared__ __align__(16) float pacc[4 * 8 * ODc];  // 20 KB [w][bb8][od]

    // stage x[b0:b0+16][itile*16:+16][8]
#pragma unroll
    for (int j = 0; j < 2; ++j) {
        int e  = t + j * 256;
        int bb = e >> 5;
        int r  = e & 31;
        ((float4*)xs)[e] =
            ((const float4*)(x + (size_t)(b0 + bb) * (Ic * 8) + itile * 128))[r];
    }

    // W fragment for (i, d): 10 o x 8 k = 80 floats (L1/L2-resident reuse)
    float4 wr[20];
    {
        const float4* wp = (const float4*)(W + (((size_t)i * Oc) * DOc + d) * 8);
#pragma unroll
        for (int o = 0; o < Oc; ++o) {
            wr[2 * o]     = wp[o * 32];
            wr[2 * o + 1] = wp[o * 32 + 1];
        }
    }
    __syncthreads();

#pragma unroll 1
    for (int half = 0; half < 2; ++half) {
#pragma unroll 1
        for (int bb8 = 0; bb8 < 8; ++bb8) {
            const int bb = half * 8 + bb8;
            const int b  = b0 + bb;
            const float4 xa = *((const float4*)(xs + bb * 128 + il * 8));
            const float4 xb = *((const float4*)(xs + bb * 128 + il * 8 + 4));
            float u[Oc];
#pragma unroll
            for (int o = 0; o < Oc; ++o) {
                float4 w0 = wr[2 * o], w1 = wr[2 * o + 1];
                u[o] = w0.x * xa.x + w0.y * xa.y + w0.z * xa.z + w0.w * xa.w +
                       w1.x * xb.x + w1.y * xb.y + w1.z * xb.z + w1.w * xb.w;
            }
            // packed ws write: one dwordx4 (o=0..7) + one dword (o=8,9)
            const size_t idx = ((size_t)b * ITILES + itile) * 256 + t;
            ws4[idx] = make_uint4(pack_h2(u[0], u[1]), pack_h2(u[2], u[3]),
                                  pack_h2(u[4], u[5]), pack_h2(u[6], u[7]));
            ws1[idx] = pack_h2(u[8], u[9]);
            // reduce over the wave's 4 il values; lane<16 holds (o,d) sums
#pragma unroll
            for (int o = 0; o < Oc; ++o) {
                float a = u[o];
                a += __shfl_xor(a, 16);
                a += __shfl_xor(a, 32);
                if ((t & 63) < 16) pacc[(w * 8 + bb8) * ODc + o * 16 + d] = a;
            }
        }
        __syncthreads();
        // flush this half: 8 bb x 160 od = 1280 floats, 5 per thread
#pragma unroll
        for (int j = 0; j < 5; ++j) {
            int e = t + j * 256;              // bb8*160 + od
            float s = pacc[e] + pacc[1280 + e] + pacc[2560 + e] + pacc[3840 + e];
            partial[(size_t)itile * (Bc * ODc) + (b0 + half * 8) * ODc + e] = s;
        }
        __syncthreads();
    }
}

// ---------------------------------------------------------------- K2/K3
// grid 1024 = b x quarter, 512 threads (8 waves). Each thread owns 9 groups
// of 16 capsules for its (il_pos, d): 90 u values packed in 45 registers,
// ALL loaded upfront (MLP = 18) before any compute.
// PASS 1: vsum = squash(0.1 * sum_{p<72} partial[p]); written to vsumg.
// PASS 2: vsum = vsumg + squash(sum of 4 sprev quarters).
template <int PASS>
__global__ __launch_bounds__(512, 4) void k_route(const uint4* __restrict__ ws4,
                                                  const unsigned int* __restrict__ ws1,
                                                  const float* __restrict__ partial,
                                                  const float* __restrict__ sprev,
                                                  float* __restrict__ vsumg,
                                                  float* __restrict__ spart) {
    const int bx   = blockIdx.x;
    const int b    = bx >> 2;
    const int q    = bx & 3;
    const int t    = threadIdx.x;
    const int d    = t & 15;
    const int pos  = t & 255;
    const int team = t >> 8;        // 0/1 (wave-uniform: waves 0-3 / 4-7)
    const int wv   = t >> 6;

    __shared__ float vs_s[ODc];
    __shared__ float red3[3 * ODc];
    __shared__ float red[8 * ODc];      // 5 KB

    // ---- issue the 18 ws loads FIRST (maximum memory-level parallelism) ----
    const size_t base = ((size_t)b * ITILES + q * 18 + team * 9) * 256 + pos;
    uint4 a4[9];
    unsigned int a1[9];
#pragma unroll
    for (int k = 0; k < 9; ++k) a4[k] = ws4[base + k * 256];
#pragma unroll
    for (int k = 0; k < 9; ++k) a1[k] = ws1[base + k * 256];

    // ---- inline vsum computation (overlaps with the loads in flight) ----
    if (PASS == 1) {
        if (t < 3 * ODc) {              // 3 teams of 160, 24 partials each
            const int tm = t / ODc;
            const int r  = t - tm * ODc;
            float s = 0.f;
            const float* pb =
                partial + (size_t)tm * 24 * (Bc * ODc) + b * ODc + r;
#pragma unroll 6
            for (int p = 0; p < 24; ++p) s += pb[(size_t)p * (Bc * ODc)];
            red3[t] = s;
        }
        __syncthreads();
        if (t < ODc) {
            float s = (red3[t] + red3[ODc + t] + red3[2 * ODc + t]) * 0.1f;
            float sq = dpp16_sum(s * s);
            float v = s * (sq / ((1.f + sq) * sqrtf(sq)));
            vs_s[t] = v;
            vsumg[b * ODc + t] = v;     // all 4 q-blocks write identical bits
        }
    } else {
        if (t < ODc) {
            float s = sprev[b * ODc + t] +
                      sprev[((size_t)Bc + b) * ODc + t] +
                      sprev[((size_t)2 * Bc + b) * ODc + t] +
                      sprev[((size_t)3 * Bc + b) * ODc + t];
            float sq = dpp16_sum(s * s);
            float v = s * (sq / ((1.f + sq) * sqrtf(sq)));
            vs_s[t] = vsumg[b * ODc + t] + v;
        }
    }
    __syncthreads();

    float vsr[Oc];
#pragma unroll
    for (int o = 0; o < Oc; ++o) vsr[o] = vs_s[o * 16 + d];
    float acc[Oc];
#pragma unroll
    for (int o = 0; o < Oc; ++o) acc[o] = 0.f;

    // ---- compute: 9 groups from registers ----
#pragma unroll
    for (int k = 0; k < 9; ++k) {
        float uo[Oc];
        {
            float2 f;
            f = unpack_h2(a4[k].x); uo[0] = f.x; uo[1] = f.y;
            f = unpack_h2(a4[k].y); uo[2] = f.x; uo[3] = f.y;
            f = unpack_h2(a4[k].z); uo[4] = f.x; uo[5] = f.y;
            f = unpack_h2(a4[k].w); uo[6] = f.x; uo[7] = f.y;
            f = unpack_h2(a1[k]);   uo[8] = f.x; uo[9] = f.y;
        }
        float c[Oc];
#pragma unroll
        for (int o = 0; o < Oc; ++o) c[o] = dpp16_sum(uo[o] * vsr[o]);
        float m = c[0];
#pragma unroll
        for (int o = 1; o < Oc; ++o) m = fmaxf(m, c[o]);
        float se = 0.f;
#pragma unroll
        for (int o = 0; o < Oc; ++o) {
            c[o] = __expf(c[o] - m);
            se += c[o];
        }
        const float inv = 1.f / se;
#pragma unroll
        for (int o = 0; o < Oc; ++o) acc[o] += (c[o] * inv) * uo[o];
    }
    // block reduce: in-wave over 4 il, then 8 waves via LDS
#pragma unroll
    for (int o = 0; o < Oc; ++o) {
        float a = acc[o];
        a += __shfl_xor(a, 16);
        a += __shfl_xor(a, 32);
        if ((t & 63) < 16) red[wv * ODc + o * 16 + d] = a;
    }
    __syncthreads();
    if (t < ODc) {
        float s = 0.f;
#pragma unroll
        for (int w = 0; w < 8; ++w) s += red[w * ODc + t];
        spart[((size_t)q * Bc + b) * ODc + t] = s;
    }
}

// ---------------------------------------------------------------- K4
__global__ __launch_bounds__(192) void k_final(const float* __restrict__ spart,
                                               float* __restrict__ out) {
    const int b = blockIdx.x;
    const int t = threadIdx.x;
    if (t >= ODc) return;
    float s = spart[b * ODc + t] +
              spart[((size_t)Bc + b) * ODc + t] +
              spart[((size_t)2 * Bc + b) * ODc + t] +
              spart[((size_t)3 * Bc + b) * ODc + t];
    float sq = dpp16_sum(s * s);
    float v = s * (sq / ((1.f + sq) * sqrtf(sq)));
    out[(size_t)b * ODc + t] = v;
}

// ---------------------------------------------------------------- fallback
__global__ void __launch_bounds__(1024, 4)
digitcaps_fallback(const float* __restrict__ x, const float* __restrict__ W,
                   float* __restrict__ out) {
    const int b = blockIdx.x, t = threadIdx.x;
    const int lane = t & 63, wid = t >> 6, d = t & 15, iblk = t >> 4;
    __shared__ __align__(16) float xs[Ic * 8];
    __shared__ __align__(16) float red[16 * ODc];
    __shared__ __align__(16) float svec[ODc], vcur[ODc], vsum[ODc];
    {
        const float4* xg = (const float4*)(x + (size_t)b * (Ic * 8));
        float4* xl = (float4*)xs;
        for (int j = t; j < Ic * 2; j += 1024) xl[j] = xg[j];
    }
    if (t < ODc) vsum[t] = 0.f;
    __syncthreads();
    float acc[Oc], vsr[Oc];
    for (int it = 0; it < 3; ++it) {
#pragma unroll
        for (int o = 0; o < Oc; ++o) { acc[o] = 0.f; vsr[o] = vsum[o * 16 + d]; }
#pragma unroll 1
        for (int chk = 0; chk < 18; ++chk) {
            const int i = chk * 64 + iblk;
            const float4 xa = ((const float4*)(xs + i * 8))[0];
            const float4 xb = ((const float4*)(xs + i * 8))[1];
            const float* wb = W + (((size_t)i * Oc) * DOc + d) * 8;
            float uo[Oc];
#pragma unroll
            for (int o = 0; o < Oc; ++o) {
                const float4* wp = (const float4*)(wb + o * 128);
                float4 w0 = wp[0], w1 = wp[1];
                uo[o] = w0.x * xa.x + w0.y * xa.y + w0.z * xa.z + w0.w * xa.w +
                        w1.x * xb.x + w1.y * xb.y + w1.z * xb.z + w1.w * xb.w;
            }
            float cc[Oc];
            if (it > 0) {
#pragma unroll
                for (int o = 0; o < Oc; ++o) cc[o] = dpp16_sum(uo[o] * vsr[o]);
                float m = cc[0];
#pragma unroll
                for (int o = 1; o < Oc; ++o) m = fmaxf(m, cc[o]);
                float se = 0.f;
#pragma unroll
                for (int o = 0; o < Oc; ++o) { cc[o] = __expf(cc[o] - m); se += cc[o]; }
                float inv = 1.f / se;
#pragma unroll
                for (int o = 0; o < Oc; ++o) acc[o] += cc[o] * inv * uo[o];
            } else {
#pragma unroll
                for (int o = 0; o < Oc; ++o) acc[o] += 0.1f * uo[o];
            }
        }
#pragma unroll
        for (int o = 0; o < Oc; ++o) {
            float a = acc[o];
            a += __shfl_xor(a, 16);
            a += __shfl_xor(a, 32);
            if (lane < 16) red[wid * ODc + o * 16 + lane] = a;
        }
        __syncthreads();
        if (t < ODc) {
            float s = 0.f;
#pragma unroll
            for (int w = 0; w < 16; ++w) s += red[w * ODc + t];
            svec[t] = s;
        }
        __syncthreads();
        if (t < Oc) {
            float sq = 0.f;
#pragma unroll
            for (int dd = 0; dd < DOc; ++dd) sq += svec[t * 16 + dd] * svec[t * 16 + dd];
            float sc = sq / ((1.f + sq) * sqrtf(sq));
#pragma unroll
            for (int dd = 0; dd < DOc; ++dd) {
                float v = svec[t * 16 + dd] * sc;
                vcur[t * 16 + dd] = v;
                vsum[t * 16 + dd] += v;
            }
        }
        __syncthreads();
    }
    if (t < ODc) out[(size_t)b * ODc + t] = vcur[t];
}

// ---------------------------------------------------------------- launcher
extern "C" void kernel_launch(void* const* d_in, const int* in_sizes, int n_in,
                              void* d_out, int out_size, void* d_ws, size_t ws_size,
                              hipStream_t stream) {
    (void)in_sizes; (void)n_in; (void)out_size;
    const float* x = (const float*)d_in[0];   // [256,1152,8]
    const float* W = (const float*)d_in[1];   // [1152,10,16,8]
    float* out     = (float*)d_out;           // [256,10,16]

    const size_t WS4_B  = (size_t)Bc * ITILES * 256 * 16;             // 75.50 MB
    const size_t WS1_B  = (size_t)Bc * ITILES * 256 * 4;              // 18.87 MB
    const size_t PART_B = (size_t)ITILES * Bc * ODc * sizeof(float);  // 11.80 MB
    const size_t SP1_B  = (size_t)4 * Bc * ODc * sizeof(float);       //  0.66 MB
    const size_t SP2_B  = (size_t)4 * Bc * ODc * sizeof(float);       //  0.66 MB
    const size_t VSUM_B = (size_t)Bc * ODc * sizeof(float);           //  0.16 MB

    char* p = (char*)d_ws;
    uint4* ws4        = (uint4*)p;                 p += WS4_B;
    unsigned int* ws1 = (unsigned int*)p;          p += WS1_B;
    float* partial    = (float*)p;                 p += PART_B;
    float* spart1     = (float*)p;                 p += SP1_B;
    float* spart2     = (float*)p;                 p += SP2_B;
    float* vsumg      = (float*)p;

    if (ws_size >= WS4_B + WS1_B + PART_B + SP1_B + SP2_B + VSUM_B) {
        hipLaunchKernelGGL(k_uhat, dim3(ITILES * 16), dim3(256), 0, stream,
                           x, W, ws4, ws1, partial);
        hipLaunchKernelGGL((k_route<1>), dim3(Bc * 4), dim3(512), 0, stream,
                           ws4, ws1, partial, nullptr, vsumg, spart1);
        hipLaunchKernelGGL((k_route<2>), dim3(Bc * 4), dim3(512), 0, stream,
                           ws4, ws1, nullptr, spart1, vsumg, spart2);
        hipLaunchKernelGGL(k_final, dim3(Bc), dim3(192), 0, stream,
                           spart2, out);
    } else {
        hipLaunchKernelGGL(digitcaps_fallback, dim3(Bc), dim3(1024), 0, stream,
                           x, W, out);
    }
}

// Round 11
// 196.805 us; speedup vs baseline: 1.1046x; 1.1046x over previous
//
#include <hip/hip_runtime.h>
#include <math.h>

// DigitCaps dynamic routing, MI355X (gfx950). Round 11: fused recompute,
// occupancy-fixed. B=256, I=1152 (dim 8), O=10 (dim 16), 3 routing iters.
//
// Measured basis:
//  - ws-materialization has a >=282 MB HBM floor (~100 us end-to-end); route
//    streams pinned at ~45 us/pass across 4 implementations. Abandoned.
//  - R5 recompute pass: FETCH 8 MB (W L2-resident per XCD, 72%8==0), VALU
//    floor ~10 us/pass, but 82 us at 2 blocks/CU (pacc 40 KB). Fix: flush
//    pacc every 2 bb -> pacc[4][2][160] = 5 KB; block covers 8 b.
//    LDS = 4+5+5 = 14 KB -> VGPR-capped ~4-5 blocks/CU (16-20 waves).
//  - launch_bounds STAYS (256,4): (256,>=5) shrinks per-wave VGPR budget and
//    spills W / per-thread arrays to scratch (R6,R7,R10 all confirmed).
//  - b_ij identity: logits at iter k = u.(v0+..+v_{k-1}) = u.vsum.
//
// Pipeline (all tiny ws: partial 11.8 MB + vsum 160 KB):
//  k_pass<0> -> k_squash<0> (vsum=v0, pre=0.1) -> k_pass<1> -> k_squash<1>
//  (vsum+=v1) -> k_pass<1> -> k_squash<2> (out=v2).

constexpr int Bc  = 256;
constexpr int Ic  = 1152;
constexpr int Oc  = 10;
constexpr int DOc = 16;
constexpr int ODc = 160;
constexpr int ITILES = 72;
constexpr int BB  = 8;               // b per block
constexpr int BT  = Bc / BB;         // 32 btiles

// Sum over the aligned 16-lane group, result in all 16 lanes. Pure VALU (DPP).
__device__ __forceinline__ float dpp16_sum(float v) {
    int s;
    s = __builtin_amdgcn_update_dpp(0, __float_as_int(v), 0xB1, 0xF, 0xF, true);
    v += __int_as_float(s);
    s = __builtin_amdgcn_update_dpp(0, __float_as_int(v), 0x4E, 0xF, 0xF, true);
    v += __int_as_float(s);
    s = __builtin_amdgcn_update_dpp(0, __float_as_int(v), 0x124, 0xF, 0xF, true);
    v += __int_as_float(s);
    s = __builtin_amdgcn_update_dpp(0, __float_as_int(v), 0x128, 0xF, 0xF, true);
    v += __int_as_float(s);
    return v;
}

// ---------------------------------------------------------------- k_pass
// grid 2304 = 72 itiles x 32 btiles, 256 threads, launch_bounds(256,4).
// Thread (il = t>>4, d = t&15) owns capsule i = itile*16+il, out-dim d; its
// 80 W floats stay L1/L2-hot across the 8 b of the btile (R5-proven shape).
// PASS 0: contrib = u (0.1 folded into squash).  PASS 1: softmax routing.
template <int PASS>
__global__ __launch_bounds__(256, 4) void k_pass(const float* __restrict__ x,
                                                 const float* __restrict__ W,
                                                 const float* __restrict__ vsum,
                                                 float* __restrict__ partial) {
    const int bx    = blockIdx.x;
    const int itile = bx % ITILES;      // 72%8==0: itile pinned to an XCD ->
    const int btile = bx / ITILES;      // W slice (738 KB/XCD) L2-resident
    const int t     = threadIdx.x;
    const int d     = t & 15;
    const int il    = t >> 4;
    const int w     = t >> 6;
    const int i     = itile * 16 + il;
    const int b0    = btile * BB;

    __shared__ __align__(16) float xs[BB * 128];      // 4 KB [bb][il*8+k]
    __shared__ __align__(16) float pacc[4 * 2 * ODc]; // 5 KB [w][sub][od]
    __shared__ __align__(16) float vs_s[BB * ODc];    // 5 KB [bb][od]

    // stage x[b0:b0+8][itile*16:+16][8]: 256 float4, one per thread
    {
        int bb = t >> 5;
        int r  = t & 31;
        ((float4*)xs)[t] =
            ((const float4*)(x + (size_t)(b0 + bb) * (Ic * 8) + itile * 128))[r];
    }
    if (PASS == 1) {
        // vsum rows for b0..b0+7: 1280 floats = 320 float4
        const float4* vg = (const float4*)(vsum + (size_t)b0 * ODc);
#pragma unroll
        for (int j = 0; j < 2; ++j) {
            int e = t + j * 256;
            if (e < 320) ((float4*)vs_s)[e] = vg[e];
        }
    }

    // W fragment for (i, d): 10 o x 8 k = 80 floats
    float4 wr[20];
    {
        const float4* wp = (const float4*)(W + (((size_t)i * Oc) * DOc + d) * 8);
#pragma unroll
        for (int o = 0; o < Oc; ++o) {
            wr[2 * o]     = wp[o * 32];
            wr[2 * o + 1] = wp[o * 32 + 1];
        }
    }
    __syncthreads();

#pragma unroll 1
    for (int pr = 0; pr < 4; ++pr) {
#pragma unroll
        for (int sub = 0; sub < 2; ++sub) {
            const int bb = pr * 2 + sub;
            const float4 xa = *((const float4*)(xs + bb * 128 + il * 8));
            const float4 xb = *((const float4*)(xs + bb * 128 + il * 8 + 4));
            float u[Oc];
#pragma unroll
            for (int o = 0; o < Oc; ++o) {
                float4 w0 = wr[2 * o], w1 = wr[2 * o + 1];
                u[o] = w0.x * xa.x + w0.y * xa.y + w0.z * xa.z + w0.w * xa.w +
                       w1.x * xb.x + w1.y * xb.y + w1.z * xb.z + w1.w * xb.w;
            }
            float contrib[Oc];
            if (PASS == 1) {
                // logits via DPP 16-lane reduce (VALU, no DS traffic)
                float c[Oc];
#pragma unroll
                for (int o = 0; o < Oc; ++o)
                    c[o] = dpp16_sum(u[o] * vs_s[bb * ODc + o * 16 + d]);
                float m = c[0];
#pragma unroll
                for (int o = 1; o < Oc; ++o) m = fmaxf(m, c[o]);
                float se = 0.f;
#pragma unroll
                for (int o = 0; o < Oc; ++o) {
                    c[o] = __expf(c[o] - m);
                    se += c[o];
                }
                const float inv = 1.f / se;
#pragma unroll
                for (int o = 0; o < Oc; ++o) contrib[o] = (c[o] * inv) * u[o];
            } else {
                // iter 0: softmax(0)=1/10 exactly; 0.1 folded into squash pre.
#pragma unroll
                for (int o = 0; o < Oc; ++o) contrib[o] = u[o];
            }
            // in-wave il-reduce; lanes<16 hold the (o,d) sums for this bb
#pragma unroll
            for (int o = 0; o < Oc; ++o) {
                float a = contrib[o];
                a += __shfl_xor(a, 16);
                a += __shfl_xor(a, 32);
                if ((t & 63) < 16) pacc[(w * 2 + sub) * ODc + o * 16 + d] = a;
            }
        }
        __syncthreads();
        // flush the pair: 2 b x 160 od = 320 floats
#pragma unroll
        for (int j = 0; j < 2; ++j) {
            int e = t + j * 256;
            if (e < 2 * ODc) {
                float s = pacc[e] + pacc[2 * ODc + e] + pacc[4 * ODc + e] +
                          pacc[6 * ODc + e];
                int row = (e >= ODc) ? 1 : 0;
                int od  = e - row * ODc;
                partial[(size_t)itile * (Bc * ODc) + (b0 + pr * 2 + row) * ODc + od] = s;
            }
        }
        __syncthreads();
    }
}

// ---------------------------------------------------------------- k_squash
// MODE 0: vsum = v   MODE 1: vsum += v   MODE 2: out = v
template <int MODE>
__global__ __launch_bounds__(256) void k_squash(const float* __restrict__ part,
                                                float* __restrict__ vsum,
                                                float* __restrict__ out,
                                                float pre) {
    const int b = blockIdx.x;
    const int t = threadIdx.x;
    if (t >= ODc) return;
    float s = 0.f;
#pragma unroll 8
    for (int p = 0; p < ITILES; ++p)
        s += part[(size_t)p * (Bc * ODc) + b * ODc + t];
    s *= pre;
    float sq = dpp16_sum(s * s);
    float scale = sq / ((1.f + sq) * sqrtf(sq));
    float v = s * scale;
    if (MODE == 0) vsum[b * ODc + t] = v;
    if (MODE == 1) vsum[b * ODc + t] += v;
    if (MODE == 2) out[(size_t)b * ODc + t] = v;
}

// ---------------------------------------------------------------- fallback
__global__ void __launch_bounds__(1024, 4)
digitcaps_fallback(const float* __restrict__ x, const float* __restrict__ W,
                   float* __restrict__ out) {
    const int b = blockIdx.x, t = threadIdx.x;
    const int lane = t & 63, wid = t >> 6, d = t & 15, iblk = t >> 4;
    __shared__ __align__(16) float xs[Ic * 8];
    __shared__ __align__(16) float red[16 * ODc];
    __shared__ __align__(16) float svec[ODc], vcur[ODc], vsum[ODc];
    {
        const float4* xg = (const float4*)(x + (size_t)b * (Ic * 8));
        float4* xl = (float4*)xs;
        for (int j = t; j < Ic * 2; j += 1024) xl[j] = xg[j];
    }
    if (t < ODc) vsum[t] = 0.f;
    __syncthreads();
    float acc[Oc], vsr[Oc];
    for (int it = 0; it < 3; ++it) {
#pragma unroll
        for (int o = 0; o < Oc; ++o) { acc[o] = 0.f; vsr[o] = vsum[o * 16 + d]; }
#pragma unroll 1
        for (int chk = 0; chk < 18; ++chk) {
            const int i = chk * 64 + iblk;
            const float4 xa = ((const float4*)(xs + i * 8))[0];
            const float4 xb = ((const float4*)(xs + i * 8))[1];
            const float* wb = W + (((size_t)i * Oc) * DOc + d) * 8;
            float uo[Oc];
#pragma unroll
            for (int o = 0; o < Oc; ++o) {
                const float4* wp = (const float4*)(wb + o * 128);
                float4 w0 = wp[0], w1 = wp[1];
                uo[o] = w0.x * xa.x + w0.y * xa.y + w0.z * xa.z + w0.w * xa.w +
                        w1.x * xb.x + w1.y * xb.y + w1.z * xb.z + w1.w * xb.w;
            }
            float cc[Oc];
            if (it > 0) {
#pragma unroll
                for (int o = 0; o < Oc; ++o) cc[o] = dpp16_sum(uo[o] * vsr[o]);
                float m = cc[0];
#pragma unroll
                for (int o = 1; o < Oc; ++o) m = fmaxf(m, cc[o]);
                float se = 0.f;
#pragma unroll
                for (int o = 0; o < Oc; ++o) { cc[o] = __expf(cc[o] - m); se += cc[o]; }
                float inv = 1.f / se;
#pragma unroll
                for (int o = 0; o < Oc; ++o) acc[o] += cc[o] * inv * uo[o];
            } else {
#pragma unroll
                for (int o = 0; o < Oc; ++o) acc[o] += 0.1f * uo[o];
            }
        }
#pragma unroll
        for (int o = 0; o < Oc; ++o) {
            float a = acc[o];
            a += __shfl_xor(a, 16);
            a += __shfl_xor(a, 32);
            if (lane < 16) red[wid * ODc + o * 16 + lane] = a;
        }
        __syncthreads();
        if (t < ODc) {
            float s = 0.f;
#pragma unroll
            for (int w = 0; w < 16; ++w) s += red[w * ODc + t];
            svec[t] = s;
        }
        __syncthreads();
        if (t < Oc) {
            float sq = 0.f;
#pragma unroll
            for (int dd = 0; dd < DOc; ++dd) sq += svec[t * 16 + dd] * svec[t * 16 + dd];
            float sc = sq / ((1.f + sq) * sqrtf(sq));
#pragma unroll
            for (int dd = 0; dd < DOc; ++dd) {
                float v = svec[t * 16 + dd] * sc;
                vcur[t * 16 + dd] = v;
                vsum[t * 16 + dd] += v;
            }
        }
        __syncthreads();
    }
    if (t < ODc) out[(size_t)b * ODc + t] = vcur[t];
}

// ---------------------------------------------------------------- launcher
extern "C" void kernel_launch(void* const* d_in, const int* in_sizes, int n_in,
                              void* d_out, int out_size, void* d_ws, size_t ws_size,
                              hipStream_t stream) {
    (void)in_sizes; (void)n_in; (void)out_size;
    const float* x = (const float*)d_in[0];   // [256,1152,8]
    const float* W = (const float*)d_in[1];   // [1152,10,16,8]
    float* out     = (float*)d_out;           // [256,10,16]

    const size_t PART_B = (size_t)ITILES * Bc * ODc * sizeof(float); // 11.8 MB
    const size_t VSUM_B = (size_t)Bc * ODc * sizeof(float);          // 160 KB

    float* partial = (float*)d_ws;
    float* vsum    = (float*)((char*)d_ws + PART_B);

    if (ws_size >= PART_B + VSUM_B) {
        dim3 pg(ITILES * BT), pb(256);
        hipLaunchKernelGGL((k_pass<0>), pg, pb, 0, stream, x, W, nullptr, partial);
        hipLaunchKernelGGL((k_squash<0>), dim3(Bc), dim3(256), 0, stream,
                           partial, vsum, out, 0.1f);
        hipLaunchKernelGGL((k_pass<1>), pg, pb, 0, stream, x, W, vsum, partial);
        hipLaunchKernelGGL((k_squash<1>), dim3(Bc), dim3(256), 0, stream,
                           partial, vsum, out, 1.f);
        hipLaunchKernelGGL((k_pass<1>), pg, pb, 0, stream, x, W, vsum, partial);
        hipLaunchKernelGGL((k_squash<2>), dim3(Bc), dim3(256), 0, stream,
                           partial, vsum, out, 1.f);
    } else {
        hipLaunchKernelGGL(digitcaps_fallback, dim3(Bc), dim3(1024), 0, stream,
                           x, W, out);
    }
}